// Round 14
// baseline (80.473 us; speedup 1.0000x reference)
//
#include <hip/hip_runtime.h>

// Problem constants
#define NB 2
#define NN 1024
#define ND 1024
#define NH 16
#define SCALE2 0.015625f              // (64^-0.5)^2
#define SCL2E 0.022542182f            // SCALE2 * log2(e): softmax runs in exp2 domain
#define DEFER_THR 11.0f               // defer-max threshold (log2 units): P <= 2^11, f16-safe
#define LNEPS 1e-5f
#define NSPLIT 2
#define JPS (16 / NSPLIT)

typedef _Float16 f16x8 __attribute__((ext_vector_type(8)));
typedef _Float16 f16x4 __attribute__((ext_vector_type(4)));
typedef float f32x4 __attribute__((ext_vector_type(4)));

// Fragment-linear layout (per b,h head): operand fragments for mfma_16x16x32_f16
// stored so one wave-load of f16x8 covers a contiguous 1KB block.
//   chunk(lane) = (r*4 + g), r=lane&15, g=lane>>4 ; element = chunk*8 + e
//   Q/K block key: (row16_block, kk)  -> flat = ((bh*64 + R16)*2 + kk)*512 + chunk*8 + e
//   V   block key: (n, jt, kk)        -> flat = (((bh*4+n)*16+jt)*2+kk)*512 + chunk*8 + e
// qfrag is stored as TWO K-halves (split-K qk GEMM); flash sums them on load.

// ---------------- helpers ----------------
__device__ inline void gload_lds16(const void* g, void* l) {
    __builtin_amdgcn_global_load_lds(
        (const __attribute__((address_space(1))) void*)g,
        (__attribute__((address_space(3))) void*)l, 16, 0, 0);
}

__device__ inline f32x4 vmax4(f32x4 a, f32x4 b) {
    f32x4 c;
    c[0] = fmaxf(a[0], b[0]); c[1] = fmaxf(a[1], b[1]);
    c[2] = fmaxf(a[2], b[2]); c[3] = fmaxf(a[3], b[3]);
    return c;
}

// ---------------- fused prep: pack x,y to f16; transpose Wq,Wk,Wv to f16 ----------------
__global__ __launch_bounds__(256) void prep(const float* __restrict__ x,
                                            const float* __restrict__ y,
                                            const float* __restrict__ Wq,
                                            const float* __restrict__ Wk,
                                            const float* __restrict__ Wv,
                                            _Float16* __restrict__ xh,
                                            _Float16* __restrict__ yh,
                                            _Float16* __restrict__ WqT,
                                            _Float16* __restrict__ WkT,
                                            _Float16* __restrict__ WvT) {
    __shared__ float tile[32][33];
    const int bid = blockIdx.x;
    const int tid = threadIdx.x;
    if (bid < 2048) {
        const float* src = (bid < 1024) ? x : y;
        _Float16* dst = (bid < 1024) ? xh : yh;
        int base = (bid & 1023) * 2048 + tid * 8;
        f32x4 a = *(const f32x4*)&src[base];
        f32x4 c = *(const f32x4*)&src[base + 4];
        *(f16x4*)&dst[base] = __builtin_convertvector(a, f16x4);
        *(f16x4*)&dst[base + 4] = __builtin_convertvector(c, f16x4);
    } else {
        int seg = (bid - 2048) >> 10;
        int t = (bid - 2048) & 1023;
        const float* src = seg == 0 ? Wq : seg == 1 ? Wk : Wv;
        _Float16* dst = seg == 0 ? WqT : seg == 1 ? WkT : WvT;
        int tx = tid & 31, ty = tid >> 5;          // (32, 8)
        int c0 = (t & 31) * 32, r0 = (t >> 5) * 32;
#pragma unroll
        for (int i = 0; i < 4; ++i)
            tile[ty + 8 * i][tx] = src[(size_t)(r0 + ty + 8 * i) * 1024 + c0 + tx];
        __syncthreads();
#pragma unroll
        for (int i = 0; i < 4; ++i)
            dst[(size_t)(c0 + ty + 8 * i) * 1024 + r0 + tx] = (_Float16)tile[tx][ty + 8 * i];
    }
}

// ---------------- f16 MFMA GEMM body, KSTEP=64, counted-vmcnt pipeline (R11-proven) ----------------
// C(MxN) = A(M x K) @ BT(N x K)^T. 4 waves 2x2, double-buffered LDS, global_load_lds(16B).
// Per K-step: issue next-tile stage -> s_waitcnt vmcnt(6) (waits only for the PREVIOUS
// tile's 6 loads, issued a full step earlier) -> raw s_barrier -> ds_read+MFMA -> raw
// s_barrier (readers done before next overwrite). No vmcnt(0) drain in the main loop.
// LDS 48 KB -> 3 blocks/CU capacity.
// mode 0: row-major f16 out0, ldc
// mode 1: K dual-write: out0 = kfrag (fragment layout), out1 = kT (col-major, ld 2048)
// mode 3: V-fragment layout (out0 = vfrag)
// mode 4: Q-fragment layout (out0 = qfrag half, zoff = b), value scaled by SCL2E
template <int BM, int BN>
__device__ __forceinline__ void gemm_body(const _Float16* __restrict__ A,
                                          const _Float16* __restrict__ BT,
                                          int lda, int ldb,
                                          int brow, int bcol, int K,
                                          int mode, _Float16* __restrict__ out0,
                                          _Float16* __restrict__ out1,
                                          int ldc, int zoff) {
    __shared__ _Float16 Asm[2][2][BM * 32];   // [buf][sub][...]
    __shared__ _Float16 Bsm[2][2][BN * 32];
    constexpr int MR = BM / 32;
    constexpr int NC = BN / 32;
    constexpr int APASS = BM * 32 * 2 / 4096;   // 4096B passes per A sub-tile
    constexpr int BPASS = BN * 32 * 2 / 4096;
    static_assert(BM * 32 * 2 % 4096 == 0 && BN * 32 * 2 % 4096 == 0, "pass alignment");
    static_assert(2 * (APASS + BPASS) == 6, "vmcnt(6) assumes 6 loads per stage");

    const int tid = threadIdx.x;
    const int lane = tid & 63;
    const int w = tid >> 6;
    const int wr = w >> 1, wc = w & 1;
    const int g = lane >> 4, r = lane & 15;

    f32x4 acc[MR][NC];
#pragma unroll
    for (int m = 0; m < MR; ++m)
#pragma unroll
        for (int n = 0; n < NC; ++n) acc[m][n] = (f32x4){0.f, 0.f, 0.f, 0.f};

    // stage one 64-wide K-step (two 32-wide sub-tiles) into buffer buf: 6 loads/thread
    auto stage = [&](int buf, int kof) {
#pragma unroll
        for (int s = 0; s < 2; ++s) {
#pragma unroll
            for (int p = 0; p < APASS; ++p) {
                int o = (p * 256 + tid) * 16;
                int row = o >> 6, cb = o & 63;    // 64B per 32-f16 row
                gload_lds16((const char*)(A + (size_t)(brow + row) * lda + kof + s * 32) + cb,
                            (char*)Asm[buf][s] + o);
            }
#pragma unroll
            for (int p = 0; p < BPASS; ++p) {
                int o = (p * 256 + tid) * 16;
                int row = o >> 6, cb = o & 63;
                gload_lds16((const char*)(BT + (size_t)(bcol + row) * ldb + kof + s * 32) + cb,
                            (char*)Bsm[buf][s] + o);
            }
        }
    };

    stage(0, 0);

    int buf = 0;
    const int nk = K / 64;
    for (int kt = 0; kt < nk; ++kt) {
        if (kt + 1 < nk) {
            stage(buf ^ 1, (kt + 1) * 64);
            // wait only for tile-kt's 6 loads (issued a full K-step ago); the 6 newest
            // (tile kt+1) stay in flight across the barrier [T4, m218]
            asm volatile("s_waitcnt vmcnt(6)" ::: "memory");
        } else {
            asm volatile("s_waitcnt vmcnt(0)" ::: "memory");
        }
        __builtin_amdgcn_s_barrier();   // all waves' tile-kt data landed in LDS

#pragma unroll
        for (int s = 0; s < 2; ++s) {
            f16x8 af[MR], bf[NC];
#pragma unroll
            for (int m = 0; m < MR; ++m)
                af[m] = *(const f16x8*)&Asm[buf][s][((BM / 2) * wr + 16 * m + r) * 32 + 8 * g];
#pragma unroll
            for (int n = 0; n < NC; ++n)
                bf[n] = *(const f16x8*)&Bsm[buf][s][((BN / 2) * wc + 16 * n + r) * 32 + 8 * g];
#pragma unroll
            for (int m = 0; m < MR; ++m)
#pragma unroll
                for (int n = 0; n < NC; ++n)
                    acc[m][n] = __builtin_amdgcn_mfma_f32_16x16x32_f16(af[m], bf[n], acc[m][n], 0, 0, 0);
        }
        __builtin_amdgcn_s_barrier();   // all waves done reading buf before next overwrite
        buf ^= 1;
    }

    // epilogue: C/D layout col = lane&15, row = (lane>>4)*4 + reg   [m89-verified]
#pragma unroll
    for (int m = 0; m < MR; ++m)
#pragma unroll
        for (int n = 0; n < NC; ++n) {
            const int colg = bcol + (BN / 2) * wc + 16 * n + r;
            const int rowbase = brow + (BM / 2) * wr + 16 * m + 4 * g;
            if (mode == 0) {
#pragma unroll
                for (int r4 = 0; r4 < 4; ++r4)
                    out0[(size_t)(rowbase + r4) * ldc + colg] = (_Float16)acc[m][n][r4];
            } else if (mode == 1) {
                f16x4 pk = __builtin_convertvector(acc[m][n], f16x4);
                *(f16x4*)&out1[(size_t)colg * 2048 + rowbase] = pk;   // kT
                int hh = colg >> 6, dh = colg & 63;
#pragma unroll
                for (int r4 = 0; r4 < 4; ++r4) {
                    int kv = rowbase + r4;
                    int bb = kv >> 10, kvl = kv & 1023;
                    size_t flat = (((size_t)((bb * 16 + hh) * 64 + (kvl >> 4)) * 2 + (dh >> 5)) << 9)
                                  + (((kvl & 15) * 4 + ((dh >> 3) & 3)) << 3) + (dh & 7);
                    out0[flat] = pk[r4];
                }
            } else if (mode == 3) {
                int hh = rowbase >> 6, mpart_ = (rowbase >> 4) & 3;
                int bb = colg >> 10, kvl = colg & 1023;
#pragma unroll
                for (int r4 = 0; r4 < 4; ++r4) {
                    int dsub = (rowbase & 63) + r4;   // 16m+4g+r4
                    size_t flat = (((size_t)((((bb * 16 + hh) * 4 + mpart_) * 16 + (kvl >> 6)) * 2
                                             + ((kvl >> 5) & 1))) << 9)
                                  + (((dsub & 15) * 4 + ((kvl >> 3) & 3)) << 3) + (kvl & 7);
                    out0[flat] = (_Float16)acc[m][n][r4];
                }
            } else {   // mode 4: qfrag half, pre-scaled into exp2 domain
                int hh = colg >> 6, dh = colg & 63;
#pragma unroll
                for (int r4 = 0; r4 < 4; ++r4) {
                    int row = rowbase + r4;
                    size_t flat = (((size_t)((zoff * 16 + hh) * 64 + (row >> 4)) * 2 + (dh >> 5)) << 9)
                                  + (((row & 15) * 4 + ((dh >> 3) & 3)) << 3) + (dh & 7);
                    out0[flat] = (_Float16)(acc[m][n][r4] * SCL2E);
                }
            }
        }
}

// ---------------- GEMM stage A: all independent GEMMs q + k + v (768 blocks = 3/CU) ----------------
__global__ __launch_bounds__(256, 3) void gemm_qkv(const _Float16* __restrict__ xh,
                                                   const _Float16* __restrict__ yh,
                                                   const _Float16* __restrict__ WqT,
                                                   const _Float16* __restrict__ WkT,
                                                   const _Float16* __restrict__ WvT,
                                                   _Float16* __restrict__ qh,
                                                   _Float16* __restrict__ kfrag,
                                                   _Float16* __restrict__ kT,
                                                   _Float16* __restrict__ vfrag) {
    const int bid = blockIdx.x;
    if (bid < 256) {
        int t = bid;
        gemm_body<128, 64>(xh, WqT, 1024, 1024, (t >> 4) * 128, (t & 15) * 64, 1024,
                           0, qh, nullptr, 1024, 0);
    } else if (bid < 512) {
        int t = bid - 256;
        gemm_body<128, 64>(yh, WkT, 1024, 1024, (t >> 4) * 128, (t & 15) * 64, 1024,
                           1, kfrag, kT, 0, 0);
    } else {
        int t = bid - 512;
        gemm_body<128, 64>(WvT, yh, 1024, 1024, (t >> 5) * 128, (t & 31) * 64, 1024,
                           3, vfrag, nullptr, 0, 0);
    }
}

// ---------------- GEMM stage B: qk, split-K x2 (512 blocks = 2/CU) ----------------
// qfrag_half[half] = SCL2E * (q[b][:, half*512:+512] @ kflat[b][half*512:+512, :])
// flash sums the two halves on load (linear, exact up to one extra f16 rounding).
__global__ __launch_bounds__(256) void gemm_qk(const _Float16* __restrict__ qh,
                                               const _Float16* __restrict__ kT,
                                               _Float16* __restrict__ qfrag) {
    const int bid = blockIdx.x;         // 0..511
    const int t = bid & 127;            // 8 x 16 tiles of 128x64
    const int zh = bid >> 7;            // 0..3
    const int z = zh >> 1, half = zh & 1;
    const size_t QHALF = (size_t)NB * NN * ND;
    gemm_body<128, 64>(qh + (size_t)z * NN * ND + half * 512,
                       kT + z * NN + half * 512,
                       1024, 2048, (t >> 4) * 128, (t & 15) * 64, 512,
                       4, qfrag + (size_t)half * QHALF, nullptr, 0, z);
}

// ---------------- MFMA flash attention: LDS-staged K/V, counted-vmcnt pipeline ----------------
// 32 Q-rows/wave (2 groups). Block stages K/V jt-tile (16KB) to LDS via global_load_lds
// (4 loads/thread), double-buffered. Per jt: issue stage(j+1) -> vmcnt(4) -> raw barrier
// -> compute -> raw barrier. Q fragments = sum of two split-K halves.
// S^T = mfma(K, Q'), O^T = mfma(V, P): lane r owns softmax row r of each group.
__global__ __launch_bounds__(256) void flash_part(const _Float16* __restrict__ Qfrag,
                                                  const _Float16* __restrict__ Kfrag,
                                                  const _Float16* __restrict__ Vfrag,
                                                  _Float16* __restrict__ opart,
                                                  float* __restrict__ mpart,
                                                  float* __restrict__ lpart) {
    __shared__ _Float16 Ks[2][4096];   // K jt-tile: 8 x 512-f16 wave-chunks
    __shared__ _Float16 Vs[2][4096];   // V jt-tile: [n][kk*512 + chunk]
    __shared__ _Float16 Ps[4][2][16][72];
    const int it = blockIdx.x;          // 0..7  (128-row i-tile)
    const int bh = blockIdx.y;          // 0..31 (= b*16+h)
    const int sp = blockIdx.z;          // 0..NSPLIT-1
    const int b = bh >> 4, h = bh & 15;

    const int tid = threadIdx.x;
    const int lane = tid & 63;
    const int w = tid >> 6;
    const int g = lane >> 4, r = lane & 15;
    const int ch8 = ((r << 2) + g) << 3;   // lane's chunk offset (f16) within a 1KB fragment block

    const _Float16* Kf = Kfrag + ((size_t)bh << 16);
    const _Float16* Vf = Vfrag + ((size_t)bh << 16);
    const size_t QHALF = (size_t)NB * NN * ND;

    // stage K/V tile jt into buffer buf: 4 loads/thread (2 K chunks + 2 V chunks)
    auto stageKV = [&](int buf, int jt) {
#pragma unroll
        for (int q = 0; q < 2; ++q) {
            int c = q * 4 + w;               // 0..7
            gload_lds16(&Kf[jt * 4096 + c * 512 + lane * 8], &Ks[buf][c * 512 + lane * 8]);
        }
#pragma unroll
        for (int q = 0; q < 2; ++q) {
            int c = q * 4 + w;               // 0..7 -> n = c>>1, half = c&1
            int n = c >> 1, half = c & 1;
            gload_lds16(&Vf[(n * 16 + jt) * 1024 + half * 512 + lane * 8],
                        &Vs[buf][n * 1024 + half * 512 + lane * 8]);
        }
    };

    // Q fragments for the wave's two 16-row groups: sum of split-K halves
    f16x8 qa[2][2];
#pragma unroll
    for (int u = 0; u < 2; ++u)
#pragma unroll
        for (int kk = 0; kk < 2; ++kk) {
            size_t qidx = ((((size_t)bh * 64 + it * 8 + w * 2 + u) * 2 + kk) << 9) + ch8;
            f16x8 a0 = *(const f16x8*)&Qfrag[qidx];
            f16x8 a1 = *(const f16x8*)&Qfrag[QHALF + qidx];
            qa[u][kk] = a0 + a1;
        }

    float m_i[2] = {-1e30f, -1e30f}, l_i[2] = {0.f, 0.f};
    f32x4 o[2][4];
#pragma unroll
    for (int u = 0; u < 2; ++u)
#pragma unroll
        for (int n = 0; n < 4; ++n) o[u][n] = (f32x4){0.f, 0.f, 0.f, 0.f};

    const int jt0 = sp * JPS;
    stageKV(0, jt0);

    int buf = 0;
    for (int j = 0; j < JPS; ++j) {
        if (j + 1 < JPS) {
            stageKV(buf ^ 1, jt0 + j + 1);
            // wait only for stage j's 4 loads (issued last iteration); stage j+1's 4
            // stay in flight across the barrier [T4]
            asm volatile("s_waitcnt vmcnt(4)" ::: "memory");
        } else {
            asm volatile("s_waitcnt vmcnt(0)" ::: "memory");
        }
        __builtin_amdgcn_s_barrier();   // stage-j K/V visible to all waves

        // ---- K fragments from LDS (contiguous ds_read_b128, conflict-free) ----
        f16x8 kfr[4][2];
#pragma unroll
        for (int f = 0; f < 4; ++f)
#pragma unroll
            for (int kk = 0; kk < 2; ++kk)
                kfr[f][kk] = *(const f16x8*)&Ks[buf][(f * 2 + kk) * 512 + ch8];

        // ---- S^T tiles (log2 domain), both groups off one K read ----
        f32x4 sT[2][4];
#pragma unroll
        for (int u = 0; u < 2; ++u)
#pragma unroll
            for (int f = 0; f < 4; ++f) sT[u][f] = (f32x4){0.f, 0.f, 0.f, 0.f};
#pragma unroll
        for (int f = 0; f < 4; ++f)
#pragma unroll
            for (int kk = 0; kk < 2; ++kk)
#pragma unroll
                for (int u = 0; u < 2; ++u)
                    sT[u][f] = __builtin_amdgcn_mfma_f32_16x16x32_f16(kfr[f][kk], qa[u][kk], sT[u][f], 0, 0, 0);

        // ---- V fragments from LDS (latency hides under softmax) ----
        f16x8 vfr[4][2];
#pragma unroll
        for (int n = 0; n < 4; ++n)
#pragma unroll
            for (int kk = 0; kk < 2; ++kk)
                vfr[n][kk] = *(const f16x8*)&Vs[buf][n * 1024 + kk * 512 + ch8];

        // ---- softmax per group: in-lane tree + 2 cross-g shuffles, defer-max ----
#pragma unroll
        for (int u = 0; u < 2; ++u) {
            f32x4 mm = vmax4(vmax4(sT[u][0], sT[u][1]), vmax4(sT[u][2], sT[u][3]));
            float mx = fmaxf(fmaxf(mm[0], mm[1]), fmaxf(mm[2], mm[3]));
            mx = fmaxf(mx, __shfl_xor(mx, 16));
            mx = fmaxf(mx, __shfl_xor(mx, 32));
            if (!__all(mx <= m_i[u] + DEFER_THR)) {
                float mnew = fmaxf(m_i[u], mx);
                float corr = exp2f(m_i[u] - mnew);
                m_i[u] = mnew;
                l_i[u] *= corr;
#pragma unroll
                for (int n = 0; n < 4; ++n) o[u][n] *= corr;
            }
            f32x4 p[4];
#pragma unroll
            for (int f = 0; f < 4; ++f)
#pragma unroll
                for (int reg = 0; reg < 4; ++reg)
                    p[f][reg] = exp2f(sT[u][f][reg] - m_i[u]);
            f32x4 ps4 = (p[0] + p[1]) + (p[2] + p[3]);
            float rs = (ps4[0] + ps4[1]) + (ps4[2] + ps4[3]);
            rs += __shfl_xor(rs, 16);
            rs += __shfl_xor(rs, 32);
            l_i[u] += rs;
#pragma unroll
            for (int f = 0; f < 4; ++f)
                *(f16x4*)&Ps[w][u][r][16 * f + 4 * g] = __builtin_convertvector(p[f], f16x4);
        }

        // ---- P B-fragments (lane r holds P-row r), lgkmcnt-ordered, wave-private ----
        f16x8 pa[2][2];
#pragma unroll
        for (int u = 0; u < 2; ++u)
#pragma unroll
            for (int kk = 0; kk < 2; ++kk)
                pa[u][kk] = *(const f16x8*)&Ps[w][u][r][kk * 32 + 8 * g];

        // ---- O^T, both groups off one V read ----
#pragma unroll
        for (int n = 0; n < 4; ++n)
#pragma unroll
            for (int kk = 0; kk < 2; ++kk)
#pragma unroll
                for (int u = 0; u < 2; ++u)
                    o[u][n] = __builtin_amdgcn_mfma_f32_16x16x32_f16(vfr[n][kk], pa[u][kk], o[u][n], 0, 0, 0);

        __builtin_amdgcn_s_barrier();   // all waves done reading buf before it is restaged
        buf ^= 1;
    }

    // epilogue: NORMALIZED partial Ohat = o / l (f16, packed 8B stores) + per-row m,l
    _Float16* Ob = opart + (size_t)sp * NB * NN * ND
                   + ((size_t)b * NN + it * 128 + 32 * w) * ND + h * 64;
#pragma unroll
    for (int u = 0; u < 2; ++u) {
        float inv = 1.0f / l_i[u];
#pragma unroll
        for (int n = 0; n < 4; ++n)
            *(f16x4*)&Ob[(size_t)(u * 16 + r) * ND + 16 * n + 4 * g] =
                __builtin_convertvector(o[u][n] * inv, f16x4);
    }
    if (lane < 16) {
        int base = (((sp * NB) + b) * NH + h) * NN + it * 128 + 32 * w + r;
        mpart[base] = m_i[0];
        lpart[base] = l_i[0];
        mpart[base + 16] = m_i[1];
        lpart[base + 16] = l_i[1];
    }
}

// ---------------- combine normalized partials + residual + LayerNorm ----------------
__global__ __launch_bounds__(256) void ln_combine(const _Float16* __restrict__ opart,
                                                  const float* __restrict__ mpart,
                                                  const float* __restrict__ lpart,
                                                  const float* __restrict__ Y,
                                                  const float* __restrict__ gamma,
                                                  const float* __restrict__ beta,
                                                  float* __restrict__ Out) {
    const int row = blockIdx.x;   // b*NN + n
    const int b = row >> 10, n = row & 1023;
    const int t = threadIdx.x;
    const int c0 = t * 4;
    const int h = c0 >> 6;

    float ms[NSPLIT], ls[NSPLIT];
    float M = -1e30f;
#pragma unroll
    for (int s = 0; s < NSPLIT; ++s) {
        int idx = (((s * NB) + b) * NH + h) * NN + n;
        ms[s] = mpart[idx];
        ls[s] = lpart[idx];
        M = fmaxf(M, ms[s]);
    }
    float wsum = 0.f;
    f32x4 acc = (f32x4){0.f, 0.f, 0.f, 0.f};
#pragma unroll
    for (int s = 0; s < NSPLIT; ++s) {
        float wgt = exp2f(ms[s] - M) * ls[s];
        wsum += wgt;
        f16x4 ov = *(const f16x4*)&opart[(size_t)s * NB * NN * ND + (size_t)row * ND + c0];
        acc += wgt * __builtin_convertvector(ov, f32x4);
    }
    f32x4 z = acc * (1.0f / wsum) + *(const f32x4*)&Y[(size_t)row * ND + c0];

    __shared__ float red[8];
    float s1 = z.x + z.y + z.z + z.w;
#pragma unroll
    for (int off = 32; off; off >>= 1) s1 += __shfl_xor(s1, off);
    if ((t & 63) == 0) red[t >> 6] = s1;
    __syncthreads();
    float mean = (red[0] + red[1] + red[2] + red[3]) * (1.0f / 1024.0f);

    f32x4 d = z - mean;
    float sq = d.x * d.x + d.y * d.y + d.z * d.z + d.w * d.w;
#pragma unroll
    for (int off = 32; off; off >>= 1) sq += __shfl_xor(sq, off);
    if ((t & 63) == 0) red[4 + (t >> 6)] = sq;
    __syncthreads();
    float var = (red[4] + red[5] + red[6] + red[7]) * (1.0f / 1024.0f);
    float rstd = rsqrtf(var + LNEPS);

    f32x4 gg = *(const f32x4*)&gamma[c0];
    f32x4 bb = *(const f32x4*)&beta[c0];
    f32x4 res = d * rstd * gg + bb;
    *(f32x4*)&Out[(size_t)row * ND + c0] = res;
}

// ---------------- launch ----------------
extern "C" void kernel_launch(void* const* d_in, const int* in_sizes, int n_in,
                              void* d_out, int out_size, void* d_ws, size_t ws_size,
                              hipStream_t stream) {
    const float* x = (const float*)d_in[0];
    const float* y = (const float*)d_in[1];
    const float* Wq = (const float*)d_in[2];
    const float* Wk = (const float*)d_in[3];
    const float* Wv = (const float*)d_in[4];
    const float* gamma = (const float*)d_in[5];
    const float* beta = (const float*)d_in[6];
    float* out = (float*)d_out;

    const size_t MB = 1024ull * 1024ull;
    char* w = (char*)d_ws;
    _Float16* xh    = (_Float16*)(w + 0 * MB);    // 4 MB
    _Float16* yh    = (_Float16*)(w + 4 * MB);    // 4 MB
    _Float16* WqT   = (_Float16*)(w + 8 * MB);    // 2 MB
    _Float16* WkT   = (_Float16*)(w + 10 * MB);   // 2 MB
    _Float16* WvT   = (_Float16*)(w + 12 * MB);   // 2 MB
    _Float16* qh    = (_Float16*)(w + 14 * MB);   // 4 MB
    _Float16* kT    = (_Float16*)(w + 18 * MB);   // 4 MB  (k^T, ld 2048)
    _Float16* kfrag = (_Float16*)(w + 22 * MB);   // 4 MB  (K fragment layout)
    _Float16* vfrag = (_Float16*)(w + 26 * MB);   // 4 MB  (V fragment layout)
    _Float16* qfrag = (_Float16*)(w + 30 * MB);   // 8 MB  (2 split-K halves, exp2-scaled)
    _Float16* opart = (_Float16*)(w + 38 * MB);   // 8 MB  (NSPLIT x 2048 x 1024 f16, normalized)
    float* mpart = (float*)(w + 46 * MB);         // 256 KB
    float* lpart = (float*)(w + 47 * MB);         // 256 KB  (total 48 MB)

    prep<<<5120, 256, 0, stream>>>(x, y, Wq, Wk, Wv, xh, yh, WqT, WkT, WvT);

    gemm_qkv<<<768, 256, 0, stream>>>(xh, yh, WqT, WkT, WvT, qh, kfrag, kT, vfrag);

    gemm_qk<<<512, 256, 0, stream>>>(qh, kT, qfrag);

    flash_part<<<dim3(8, 32, NSPLIT), 256, 0, stream>>>(qfrag, kfrag, vfrag, opart, mpart, lpart);

    ln_combine<<<NB * NN, 256, 0, stream>>>(opart, mpart, lpart, y, gamma, beta, out);
}

// Round 15
// 77.652 us; speedup vs baseline: 1.0363x; 1.0363x over previous
//
#include <hip/hip_runtime.h>

// Problem constants
#define NB 2
#define NN 1024
#define ND 1024
#define NH 16
#define SCALE2 0.015625f              // (64^-0.5)^2
#define SCL2E 0.022542182f            // SCALE2 * log2(e): softmax runs in exp2 domain
#define DEFER_THR 11.0f               // defer-max threshold (log2 units): P <= 2^11, f16-safe
#define LNEPS 1e-5f
#define NSPLIT 2
#define JPS (16 / NSPLIT)

typedef _Float16 f16x8 __attribute__((ext_vector_type(8)));
typedef _Float16 f16x4 __attribute__((ext_vector_type(4)));
typedef float f32x4 __attribute__((ext_vector_type(4)));

// Fragment-linear layout (per b,h head): operand fragments for mfma_16x16x32_f16
// stored so one wave-load of f16x8 covers a contiguous 1KB block.
//   chunk(lane) = (r*4 + g), r=lane&15, g=lane>>4 ; element = chunk*8 + e
//   Q/K block key: (row16_block, kk)  -> flat = ((bh*64 + R16)*2 + kk)*512 + chunk*8 + e
//   V   block key: (n, jt, kk)        -> flat = (((bh*4+n)*16+jt)*2+kk)*512 + chunk*8 + e

// ---------------- helpers ----------------
__device__ inline void gload_lds16(const void* g, void* l) {
    __builtin_amdgcn_global_load_lds(
        (const __attribute__((address_space(1))) void*)g,
        (__attribute__((address_space(3))) void*)l, 16, 0, 0);
}

__device__ inline f32x4 vmax4(f32x4 a, f32x4 b) {
    f32x4 c;
    c[0] = fmaxf(a[0], b[0]); c[1] = fmaxf(a[1], b[1]);
    c[2] = fmaxf(a[2], b[2]); c[3] = fmaxf(a[3], b[3]);
    return c;
}

// ---------------- fused prep: pack x,y to f16; transpose Wq,Wk,Wv to f16 ----------------
__global__ __launch_bounds__(256) void prep(const float* __restrict__ x,
                                            const float* __restrict__ y,
                                            const float* __restrict__ Wq,
                                            const float* __restrict__ Wk,
                                            const float* __restrict__ Wv,
                                            _Float16* __restrict__ xh,
                                            _Float16* __restrict__ yh,
                                            _Float16* __restrict__ WqT,
                                            _Float16* __restrict__ WkT,
                                            _Float16* __restrict__ WvT) {
    __shared__ float tile[32][33];
    const int bid = blockIdx.x;
    const int tid = threadIdx.x;
    if (bid < 2048) {
        const float* src = (bid < 1024) ? x : y;
        _Float16* dst = (bid < 1024) ? xh : yh;
        int base = (bid & 1023) * 2048 + tid * 8;
        f32x4 a = *(const f32x4*)&src[base];
        f32x4 c = *(const f32x4*)&src[base + 4];
        *(f16x4*)&dst[base] = __builtin_convertvector(a, f16x4);
        *(f16x4*)&dst[base + 4] = __builtin_convertvector(c, f16x4);
    } else {
        int seg = (bid - 2048) >> 10;
        int t = (bid - 2048) & 1023;
        const float* src = seg == 0 ? Wq : seg == 1 ? Wk : Wv;
        _Float16* dst = seg == 0 ? WqT : seg == 1 ? WkT : WvT;
        int tx = tid & 31, ty = tid >> 5;          // (32, 8)
        int c0 = (t & 31) * 32, r0 = (t >> 5) * 32;
#pragma unroll
        for (int i = 0; i < 4; ++i)
            tile[ty + 8 * i][tx] = src[(size_t)(r0 + ty + 8 * i) * 1024 + c0 + tx];
        __syncthreads();
#pragma unroll
        for (int i = 0; i < 4; ++i)
            dst[(size_t)(c0 + ty + 8 * i) * 1024 + r0 + tx] = (_Float16)tile[tx][ty + 8 * i];
    }
}

// ---------------- f16 MFMA GEMM body, KSTEP=64, counted-vmcnt pipeline (R11/R13-proven) ----------------
// C(MxN) = A(M x K) @ BT(N x K)^T. 4 waves 2x2, double-buffered LDS, global_load_lds(16B).
// Per K-step: issue next-tile stage -> s_waitcnt vmcnt(6) (waits only for the PREVIOUS
// tile's 6 loads, issued a full step earlier) -> raw s_barrier -> ds_read+MFMA -> raw
// s_barrier (readers done before next overwrite). No vmcnt(0) drain in the main loop.
// mode 0: row-major f16 out0, ldc
// mode 1: K dual-write: out0 = kfrag (fragment layout), out1 = kT (col-major, ld 2048)
// mode 3: V-fragment layout (out0 = vfrag)
// mode 4: Q-fragment layout (out0 = qfrag, zoff = b), value scaled by SCL2E (exp2 domain)
template <int BM, int BN>
__device__ __forceinline__ void gemm_body(const _Float16* __restrict__ A,
                                          const _Float16* __restrict__ BT,
                                          int lda, int ldb,
                                          int brow, int bcol, int K,
                                          int mode, _Float16* __restrict__ out0,
                                          _Float16* __restrict__ out1,
                                          int ldc, int zoff) {
    __shared__ _Float16 Asm[2][2][BM * 32];   // [buf][sub][...]
    __shared__ _Float16 Bsm[2][2][BN * 32];
    constexpr int MR = BM / 32;
    constexpr int NC = BN / 32;
    constexpr int APASS = BM * 32 * 2 / 4096;   // 4096B passes per A sub-tile
    constexpr int BPASS = BN * 32 * 2 / 4096;
    static_assert(BM * 32 * 2 % 4096 == 0 && BN * 32 * 2 % 4096 == 0, "pass alignment");
    static_assert(2 * (APASS + BPASS) == 6, "vmcnt(6) assumes 6 loads per stage");

    const int tid = threadIdx.x;
    const int lane = tid & 63;
    const int w = tid >> 6;
    const int wr = w >> 1, wc = w & 1;
    const int g = lane >> 4, r = lane & 15;

    f32x4 acc[MR][NC];
#pragma unroll
    for (int m = 0; m < MR; ++m)
#pragma unroll
        for (int n = 0; n < NC; ++n) acc[m][n] = (f32x4){0.f, 0.f, 0.f, 0.f};

    // stage one 64-wide K-step (two 32-wide sub-tiles) into buffer buf: 6 loads/thread
    auto stage = [&](int buf, int kof) {
#pragma unroll
        for (int s = 0; s < 2; ++s) {
#pragma unroll
            for (int p = 0; p < APASS; ++p) {
                int o = (p * 256 + tid) * 16;
                int row = o >> 6, cb = o & 63;    // 64B per 32-f16 row
                gload_lds16((const char*)(A + (size_t)(brow + row) * lda + kof + s * 32) + cb,
                            (char*)Asm[buf][s] + o);
            }
#pragma unroll
            for (int p = 0; p < BPASS; ++p) {
                int o = (p * 256 + tid) * 16;
                int row = o >> 6, cb = o & 63;
                gload_lds16((const char*)(BT + (size_t)(bcol + row) * ldb + kof + s * 32) + cb,
                            (char*)Bsm[buf][s] + o);
            }
        }
    };

    stage(0, 0);

    int buf = 0;
    const int nk = K / 64;
    for (int kt = 0; kt < nk; ++kt) {
        if (kt + 1 < nk) {
            stage(buf ^ 1, (kt + 1) * 64);
            // wait only for tile-kt's 6 loads (issued a full K-step ago); the 6 newest
            // (tile kt+1) stay in flight across the barrier [T4, m218]
            asm volatile("s_waitcnt vmcnt(6)" ::: "memory");
        } else {
            asm volatile("s_waitcnt vmcnt(0)" ::: "memory");
        }
        __builtin_amdgcn_s_barrier();   // all waves' tile-kt data landed in LDS

#pragma unroll
        for (int s = 0; s < 2; ++s) {
            f16x8 af[MR], bf[NC];
#pragma unroll
            for (int m = 0; m < MR; ++m)
                af[m] = *(const f16x8*)&Asm[buf][s][((BM / 2) * wr + 16 * m + r) * 32 + 8 * g];
#pragma unroll
            for (int n = 0; n < NC; ++n)
                bf[n] = *(const f16x8*)&Bsm[buf][s][((BN / 2) * wc + 16 * n + r) * 32 + 8 * g];
#pragma unroll
            for (int m = 0; m < MR; ++m)
#pragma unroll
                for (int n = 0; n < NC; ++n)
                    acc[m][n] = __builtin_amdgcn_mfma_f32_16x16x32_f16(af[m], bf[n], acc[m][n], 0, 0, 0);
        }
        __builtin_amdgcn_s_barrier();   // all waves done reading buf before next overwrite
        buf ^= 1;
    }

    // epilogue: C/D layout col = lane&15, row = (lane>>4)*4 + reg   [m89-verified]
#pragma unroll
    for (int m = 0; m < MR; ++m)
#pragma unroll
        for (int n = 0; n < NC; ++n) {
            const int colg = bcol + (BN / 2) * wc + 16 * n + r;
            const int rowbase = brow + (BM / 2) * wr + 16 * m + 4 * g;
            if (mode == 0) {
#pragma unroll
                for (int r4 = 0; r4 < 4; ++r4)
                    out0[(size_t)(rowbase + r4) * ldc + colg] = (_Float16)acc[m][n][r4];
            } else if (mode == 1) {
                f16x4 pk = __builtin_convertvector(acc[m][n], f16x4);
                *(f16x4*)&out1[(size_t)colg * 2048 + rowbase] = pk;   // kT
                int hh = colg >> 6, dh = colg & 63;
#pragma unroll
                for (int r4 = 0; r4 < 4; ++r4) {
                    int kv = rowbase + r4;
                    int bb = kv >> 10, kvl = kv & 1023;
                    size_t flat = (((size_t)((bb * 16 + hh) * 64 + (kvl >> 4)) * 2 + (dh >> 5)) << 9)
                                  + (((kvl & 15) * 4 + ((dh >> 3) & 3)) << 3) + (dh & 7);
                    out0[flat] = pk[r4];
                }
            } else if (mode == 3) {
                int hh = rowbase >> 6, mpart_ = (rowbase >> 4) & 3;
                int bb = colg >> 10, kvl = colg & 1023;
#pragma unroll
                for (int r4 = 0; r4 < 4; ++r4) {
                    int dsub = (rowbase & 63) + r4;   // 16m+4g+r4
                    size_t flat = (((size_t)((((bb * 16 + hh) * 4 + mpart_) * 16 + (kvl >> 6)) * 2
                                             + ((kvl >> 5) & 1))) << 9)
                                  + (((dsub & 15) * 4 + ((kvl >> 3) & 3)) << 3) + (kvl & 7);
                    out0[flat] = (_Float16)acc[m][n][r4];
                }
            } else {   // mode 4: qfrag, pre-scaled into exp2 domain
                int hh = colg >> 6, dh = colg & 63;
#pragma unroll
                for (int r4 = 0; r4 < 4; ++r4) {
                    int row = rowbase + r4;
                    size_t flat = (((size_t)((zoff * 16 + hh) * 64 + (row >> 4)) * 2 + (dh >> 5)) << 9)
                                  + (((row & 15) * 4 + ((dh >> 3) & 3)) << 3) + (dh & 7);
                    out0[flat] = (_Float16)(acc[m][n][r4] * SCL2E);
                }
            }
        }
}

// ---------------- GEMM stage A: q + k (512 blocks) ----------------
__global__ __launch_bounds__(256) void gemm_a(const _Float16* __restrict__ xh,
                                              const _Float16* __restrict__ yh,
                                              const _Float16* __restrict__ WqT,
                                              const _Float16* __restrict__ WkT,
                                              _Float16* __restrict__ qh,
                                              _Float16* __restrict__ kfrag,
                                              _Float16* __restrict__ kT) {
    const int bid = blockIdx.x;
    const int t = bid & 255;
    if (bid < 256)
        gemm_body<128, 64>(xh, WqT, 1024, 1024, (t >> 4) * 128, (t & 15) * 64, 1024,
                           0, qh, nullptr, 1024, 0);
    else
        gemm_body<128, 64>(yh, WkT, 1024, 1024, (t >> 4) * 128, (t & 15) * 64, 1024,
                           1, kfrag, kT, 0, 0);
}

// ---------------- GEMM stage B: qk (128x64 tiles) + independent v (512 blocks) ----------------
__global__ __launch_bounds__(256) void gemm_b(const _Float16* __restrict__ qh,
                                              const _Float16* __restrict__ kT,
                                              const _Float16* __restrict__ yh,
                                              const _Float16* __restrict__ WvT,
                                              _Float16* __restrict__ qfrag,
                                              _Float16* __restrict__ vfrag) {
    const int bid = blockIdx.x;
    if (bid < 256) {
        int z = bid >> 7, t = bid & 127;
        gemm_body<128, 64>(qh + (size_t)z * NN * ND, kT + z * NN, 1024, 2048,
                           (t >> 4) * 128, (t & 15) * 64, 1024, 4, qfrag, nullptr, 0, z);
    } else {
        int t = bid - 256;
        gemm_body<128, 64>(WvT, yh, 1024, 1024, (t >> 5) * 128, (t & 31) * 64, 1024,
                           3, vfrag, nullptr, 0, 0);
    }
}

// ---------------- MFMA flash attention: LDS-staged K/V, counted-vmcnt pipeline ----------------
// 32 Q-rows/wave (2 groups). Block stages K/V jt-tile (16KB) to LDS via global_load_lds
// (4 loads/thread), double-buffered. Per jt: issue stage(j+1) -> vmcnt(4) (waits only for
// stage j, issued one iteration earlier) -> raw barrier -> compute -> raw barrier.
// S^T = mfma(K, Q'), O^T = mfma(V, P): lane r owns softmax row r of each group.
__global__ __launch_bounds__(256) void flash_part(const _Float16* __restrict__ Qfrag,
                                                  const _Float16* __restrict__ Kfrag,
                                                  const _Float16* __restrict__ Vfrag,
                                                  _Float16* __restrict__ opart,
                                                  float* __restrict__ mpart,
                                                  float* __restrict__ lpart) {
    __shared__ _Float16 Ks[2][4096];   // K jt-tile: 8 x 512-f16 wave-chunks
    __shared__ _Float16 Vs[2][4096];   // V jt-tile: [n][kk*512 + chunk]
    __shared__ _Float16 Ps[4][2][16][72];
    const int it = blockIdx.x;          // 0..7  (128-row i-tile)
    const int bh = blockIdx.y;          // 0..31 (= b*16+h)
    const int sp = blockIdx.z;          // 0..NSPLIT-1
    const int b = bh >> 4, h = bh & 15;

    const int tid = threadIdx.x;
    const int lane = tid & 63;
    const int w = tid >> 6;
    const int g = lane >> 4, r = lane & 15;
    const int ch8 = ((r << 2) + g) << 3;   // lane's chunk offset (f16) within a 1KB fragment block

    const _Float16* Kf = Kfrag + ((size_t)bh << 16);
    const _Float16* Vf = Vfrag + ((size_t)bh << 16);

    // stage K/V tile jt into buffer buf: 4 loads/thread (2 K chunks + 2 V chunks)
    auto stageKV = [&](int buf, int jt) {
#pragma unroll
        for (int q = 0; q < 2; ++q) {
            int c = q * 4 + w;               // 0..7
            gload_lds16(&Kf[jt * 4096 + c * 512 + lane * 8], &Ks[buf][c * 512 + lane * 8]);
        }
#pragma unroll
        for (int q = 0; q < 2; ++q) {
            int c = q * 4 + w;               // 0..7 -> n = c>>1, half = c&1
            int n = c >> 1, half = c & 1;
            gload_lds16(&Vf[(n * 16 + jt) * 1024 + half * 512 + lane * 8],
                        &Vs[buf][n * 1024 + half * 512 + lane * 8]);
        }
    };

    // Q fragments for the wave's two 16-row groups: R16 = it*8 + w*2 + u
    f16x8 qa[2][2];
#pragma unroll
    for (int u = 0; u < 2; ++u)
#pragma unroll
        for (int kk = 0; kk < 2; ++kk)
            qa[u][kk] = *(const f16x8*)
                &Qfrag[((((size_t)bh * 64 + it * 8 + w * 2 + u) * 2 + kk) << 9) + ch8];

    float m_i[2] = {-1e30f, -1e30f}, l_i[2] = {0.f, 0.f};
    f32x4 o[2][4];
#pragma unroll
    for (int u = 0; u < 2; ++u)
#pragma unroll
        for (int n = 0; n < 4; ++n) o[u][n] = (f32x4){0.f, 0.f, 0.f, 0.f};

    const int jt0 = sp * JPS;
    stageKV(0, jt0);

    int buf = 0;
    for (int j = 0; j < JPS; ++j) {
        if (j + 1 < JPS) {
            stageKV(buf ^ 1, jt0 + j + 1);
            // wait only for stage j's 4 loads (issued last iteration); stage j+1's 4
            // stay in flight across the barrier [T4]
            asm volatile("s_waitcnt vmcnt(4)" ::: "memory");
        } else {
            asm volatile("s_waitcnt vmcnt(0)" ::: "memory");
        }
        __builtin_amdgcn_s_barrier();   // stage-j K/V visible to all waves

        // ---- K fragments from LDS (contiguous ds_read_b128, conflict-free) ----
        f16x8 kfr[4][2];
#pragma unroll
        for (int f = 0; f < 4; ++f)
#pragma unroll
            for (int kk = 0; kk < 2; ++kk)
                kfr[f][kk] = *(const f16x8*)&Ks[buf][(f * 2 + kk) * 512 + ch8];

        // ---- S^T tiles (log2 domain), both groups off one K read ----
        f32x4 sT[2][4];
#pragma unroll
        for (int u = 0; u < 2; ++u)
#pragma unroll
            for (int f = 0; f < 4; ++f) sT[u][f] = (f32x4){0.f, 0.f, 0.f, 0.f};
#pragma unroll
        for (int f = 0; f < 4; ++f)
#pragma unroll
            for (int kk = 0; kk < 2; ++kk)
#pragma unroll
                for (int u = 0; u < 2; ++u)
                    sT[u][f] = __builtin_amdgcn_mfma_f32_16x16x32_f16(kfr[f][kk], qa[u][kk], sT[u][f], 0, 0, 0);

        // ---- V fragments from LDS (latency hides under softmax) ----
        f16x8 vfr[4][2];
#pragma unroll
        for (int n = 0; n < 4; ++n)
#pragma unroll
            for (int kk = 0; kk < 2; ++kk)
                vfr[n][kk] = *(const f16x8*)&Vs[buf][n * 1024 + kk * 512 + ch8];

        // ---- softmax per group: in-lane tree + 2 cross-g shuffles, defer-max ----
#pragma unroll
        for (int u = 0; u < 2; ++u) {
            f32x4 mm = vmax4(vmax4(sT[u][0], sT[u][1]), vmax4(sT[u][2], sT[u][3]));
            float mx = fmaxf(fmaxf(mm[0], mm[1]), fmaxf(mm[2], mm[3]));
            mx = fmaxf(mx, __shfl_xor(mx, 16));
            mx = fmaxf(mx, __shfl_xor(mx, 32));
            if (!__all(mx <= m_i[u] + DEFER_THR)) {
                float mnew = fmaxf(m_i[u], mx);
                float corr = exp2f(m_i[u] - mnew);
                m_i[u] = mnew;
                l_i[u] *= corr;
#pragma unroll
                for (int n = 0; n < 4; ++n) o[u][n] *= corr;
            }
            f32x4 p[4];
#pragma unroll
            for (int f = 0; f < 4; ++f)
#pragma unroll
                for (int reg = 0; reg < 4; ++reg)
                    p[f][reg] = exp2f(sT[u][f][reg] - m_i[u]);
            f32x4 ps4 = (p[0] + p[1]) + (p[2] + p[3]);
            float rs = (ps4[0] + ps4[1]) + (ps4[2] + ps4[3]);
            rs += __shfl_xor(rs, 16);
            rs += __shfl_xor(rs, 32);
            l_i[u] += rs;
#pragma unroll
            for (int f = 0; f < 4; ++f)
                *(f16x4*)&Ps[w][u][r][16 * f + 4 * g] = __builtin_convertvector(p[f], f16x4);
        }

        // ---- P B-fragments (lane r holds P-row r), lgkmcnt-ordered, wave-private ----
        f16x8 pa[2][2];
#pragma unroll
        for (int u = 0; u < 2; ++u)
#pragma unroll
            for (int kk = 0; kk < 2; ++kk)
                pa[u][kk] = *(const f16x8*)&Ps[w][u][r][kk * 32 + 8 * g];

        // ---- O^T, both groups off one V read ----
#pragma unroll
        for (int n = 0; n < 4; ++n)
#pragma unroll
            for (int kk = 0; kk < 2; ++kk)
#pragma unroll
                for (int u = 0; u < 2; ++u)
                    o[u][n] = __builtin_amdgcn_mfma_f32_16x16x32_f16(vfr[n][kk], pa[u][kk], o[u][n], 0, 0, 0);

        __builtin_amdgcn_s_barrier();   // all waves done reading buf before it is restaged
        buf ^= 1;
    }

    // epilogue: NORMALIZED partial Ohat = o / l (f16, packed 8B stores) + per-row m,l
    _Float16* Ob = opart + (size_t)sp * NB * NN * ND
                   + ((size_t)b * NN + it * 128 + 32 * w) * ND + h * 64;
#pragma unroll
    for (int u = 0; u < 2; ++u) {
        float inv = 1.0f / l_i[u];
#pragma unroll
        for (int n = 0; n < 4; ++n)
            *(f16x4*)&Ob[(size_t)(u * 16 + r) * ND + 16 * n + 4 * g] =
                __builtin_convertvector(o[u][n] * inv, f16x4);
    }
    if (lane < 16) {
        int base = (((sp * NB) + b) * NH + h) * NN + it * 128 + 32 * w + r;
        mpart[base] = m_i[0];
        lpart[base] = l_i[0];
        mpart[base + 16] = m_i[1];
        lpart[base + 16] = l_i[1];
    }
}

// ---------------- combine normalized partials + residual + LayerNorm (fused moments) ----------------
// Single reduction pass: sum(z) and sum(z^2) reduced together; var = E[z^2] - mean^2
// (cancellation benign: |mean| << std here). One __syncthreads instead of two.
__global__ __launch_bounds__(256) void ln_combine(const _Float16* __restrict__ opart,
                                                  const float* __restrict__ mpart,
                                                  const float* __restrict__ lpart,
                                                  const float* __restrict__ Y,
                                                  const float* __restrict__ gamma,
                                                  const float* __restrict__ beta,
                                                  float* __restrict__ Out) {
    const int row = blockIdx.x;   // b*NN + n
    const int b = row >> 10, n = row & 1023;
    const int t = threadIdx.x;
    const int c0 = t * 4;
    const int h = c0 >> 6;

    float ms[NSPLIT], ls[NSPLIT];
    float M = -1e30f;
#pragma unroll
    for (int s = 0; s < NSPLIT; ++s) {
        int idx = (((s * NB) + b) * NH + h) * NN + n;
        ms[s] = mpart[idx];
        ls[s] = lpart[idx];
        M = fmaxf(M, ms[s]);
    }
    float wsum = 0.f;
    f32x4 acc = (f32x4){0.f, 0.f, 0.f, 0.f};
#pragma unroll
    for (int s = 0; s < NSPLIT; ++s) {
        float wgt = exp2f(ms[s] - M) * ls[s];
        wsum += wgt;
        f16x4 ov = *(const f16x4*)&opart[(size_t)s * NB * NN * ND + (size_t)row * ND + c0];
        acc += wgt * __builtin_convertvector(ov, f32x4);
    }
    f32x4 z = acc * (1.0f / wsum) + *(const f32x4*)&Y[(size_t)row * ND + c0];

    // fused two-moment reduction: (sum, sumsq) in one shuffle chain + one barrier
    __shared__ float red[8];
    float s1 = z.x + z.y + z.z + z.w;
    float sq = z.x * z.x + z.y * z.y + z.z * z.z + z.w * z.w;
#pragma unroll
    for (int off = 32; off; off >>= 1) {
        s1 += __shfl_xor(s1, off);
        sq += __shfl_xor(sq, off);
    }
    if ((t & 63) == 0) { red[t >> 6] = s1; red[4 + (t >> 6)] = sq; }
    __syncthreads();
    float mean = (red[0] + red[1] + red[2] + red[3]) * (1.0f / 1024.0f);
    float ez2 = (red[4] + red[5] + red[6] + red[7]) * (1.0f / 1024.0f);
    float var = ez2 - mean * mean;
    float rstd = rsqrtf(var + LNEPS);

    f32x4 d = z - mean;
    f32x4 gg = *(const f32x4*)&gamma[c0];
    f32x4 bb = *(const f32x4*)&beta[c0];
    f32x4 res = d * rstd * gg + bb;
    *(f32x4*)&Out[(size_t)row * ND + c0] = res;
}

// ---------------- launch ----------------
extern "C" void kernel_launch(void* const* d_in, const int* in_sizes, int n_in,
                              void* d_out, int out_size, void* d_ws, size_t ws_size,
                              hipStream_t stream) {
    const float* x = (const float*)d_in[0];
    const float* y = (const float*)d_in[1];
    const float* Wq = (const float*)d_in[2];
    const float* Wk = (const float*)d_in[3];
    const float* Wv = (const float*)d_in[4];
    const float* gamma = (const float*)d_in[5];
    const float* beta = (const float*)d_in[6];
    float* out = (float*)d_out;

    const size_t MB = 1024ull * 1024ull;
    char* w = (char*)d_ws;
    _Float16* xh    = (_Float16*)(w + 0 * MB);    // 4 MB
    _Float16* yh    = (_Float16*)(w + 4 * MB);    // 4 MB
    _Float16* WqT   = (_Float16*)(w + 8 * MB);    // 2 MB
    _Float16* WkT   = (_Float16*)(w + 10 * MB);   // 2 MB
    _Float16* WvT   = (_Float16*)(w + 12 * MB);   // 2 MB
    _Float16* qh    = (_Float16*)(w + 14 * MB);   // 4 MB
    _Float16* kT    = (_Float16*)(w + 18 * MB);   // 4 MB  (k^T, ld 2048)
    _Float16* kfrag = (_Float16*)(w + 22 * MB);   // 4 MB  (K fragment layout)
    _Float16* vfrag = (_Float16*)(w + 26 * MB);   // 4 MB  (V fragment layout)
    _Float16* qfrag = (_Float16*)(w + 30 * MB);   // 4 MB  (Q' fragment layout, exp2-scaled)
    _Float16* opart = (_Float16*)(w + 34 * MB);   // 8 MB  (NSPLIT x 2048 x 1024 f16, normalized)
    float* mpart = (float*)(w + 42 * MB);         // 256 KB
    float* lpart = (float*)(w + 43 * MB);         // 256 KB  (total 44 MB)

    prep<<<5120, 256, 0, stream>>>(x, y, Wq, Wk, Wv, xh, yh, WqT, WkT, WvT);

    gemm_a<<<512, 256, 0, stream>>>(xh, yh, WqT, WkT, qh, kfrag, kT);

    gemm_b<<<512, 256, 0, stream>>>(qh, kT, yh, WvT, qfrag, vfrag);

    flash_part<<<dim3(8, 32, NSPLIT), 256, 0, stream>>>(qfrag, kfrag, vfrag, opart, mpart, lpart);

    ln_combine<<<NB * NN, 256, 0, stream>>>(opart, mpart, lpart, y, gamma, beta, out);
}